// Round 1
// baseline (487.334 us; speedup 1.0000x reference)
//
#include <hip/hip_runtime.h>

// CausalAttention: B=8, S=2048, D_IN=D_OUT=1024, single head, causal, fp32 I/O.
// Pipeline (all fp16 MFMA 16x16x32, fp32 accum):
//   1. cast x -> xh (fp16)
//   2. transpose+cast Wq,Wk,Wv -> WT (d_out-major, fp16)
//   3. GEMM: Q = xh@Wq, K = xh@Wk (row-major), V -> Vt (transposed output)
//   4. score kernel: U[b,q,k] = exp(q.k/32) fp16, causal tiles only, masked diag
//   5. rowsum: invl[b,q] = 1/sum_k U
//   6. PV GEMM: out = (U @ V) * invl   (fp32 stores)

#define Bv   8
#define Sv   2048
#define Dv   1024
#define LSTR 40   // LDS row stride (elems): 80B rows -> 16B aligned, 2-way-max banks

typedef _Float16 f16x8 __attribute__((ext_vector_type(8)));
typedef _Float16 f16x4 __attribute__((ext_vector_type(4)));
typedef float    f32x4 __attribute__((ext_vector_type(4)));

__device__ __forceinline__ void stage_tile(const _Float16* __restrict__ g, int ld,
                                           _Float16* lds, int tid) {
  // 128 rows x 32 k, 256 threads, 2 x 16B loads each
#pragma unroll
  for (int i = 0; i < 2; ++i) {
    int idx = i * 256 + tid;
    int row = idx >> 2;
    int c8  = (idx & 3) << 3;
    f16x8 v = *(const f16x8*)(g + (size_t)row * ld + c8);
    *(f16x8*)(lds + row * LSTR + c8) = v;
  }
}

__device__ __forceinline__ void mma_step(const _Float16* As, const _Float16* Bs,
                                         int wm, int wn, int lane, f32x4 acc[4][4]) {
  int ll = lane & 15, quad = lane >> 4;
  f16x8 a[4], b[4];
#pragma unroll
  for (int mi = 0; mi < 4; ++mi)
    a[mi] = *(const f16x8*)(As + (wm * 64 + mi * 16 + ll) * LSTR + quad * 8);
#pragma unroll
  for (int ni = 0; ni < 4; ++ni)
    b[ni] = *(const f16x8*)(Bs + (wn * 64 + ni * 16 + ll) * LSTR + quad * 8);
#pragma unroll
  for (int mi = 0; mi < 4; ++mi)
#pragma unroll
    for (int ni = 0; ni < 4; ++ni)
      acc[mi][ni] = __builtin_amdgcn_mfma_f32_16x16x32_f16(a[mi], b[ni], acc[mi][ni], 0, 0, 0);
}

__device__ __forceinline__ void gemm_core(const _Float16* __restrict__ A, int lda,
                                          const _Float16* __restrict__ B, int ldb,
                                          int ktiles, _Float16* As, _Float16* Bs,
                                          f32x4 acc[4][4]) {
  int tid  = threadIdx.x;
  int lane = tid & 63, wave = tid >> 6;
  int wm = wave >> 1, wn = wave & 1;
  for (int kt = 0; kt < ktiles; ++kt) {
    stage_tile(A + kt * 32, lda, As, tid);
    stage_tile(B + kt * 32, ldb, Bs, tid);
    __syncthreads();
    mma_step(As, Bs, wm, wn, lane, acc);
    __syncthreads();
  }
}

#define ZERO_ACC(acc)                              \
  _Pragma("unroll") for (int i_ = 0; i_ < 4; ++i_) \
  _Pragma("unroll") for (int j_ = 0; j_ < 4; ++j_) \
      acc[i_][j_] = (f32x4){0.f, 0.f, 0.f, 0.f};

// --- 1. cast x (fp32) -> fp16, 8 elems/thread ---
__global__ __launch_bounds__(256) void ca_cast(const float* __restrict__ x,
                                               _Float16* __restrict__ y) {
  int i = (blockIdx.x * 256 + threadIdx.x) * 8;
  f32x4 a = *(const f32x4*)(x + i);
  f32x4 b = *(const f32x4*)(x + i + 4);
  f16x8 h;
#pragma unroll
  for (int j = 0; j < 4; ++j) { h[j] = (_Float16)a[j]; h[4 + j] = (_Float16)b[j]; }
  *(f16x8*)(y + i) = h;
}

// --- 2. transpose+cast W (K x N fp32) -> WT (N x K fp16) ---
__global__ __launch_bounds__(256) void ca_transpose(const float* __restrict__ W,
                                                    _Float16* __restrict__ WT) {
  __shared__ _Float16 t[32][33];
  int k0 = blockIdx.x * 32, n0 = blockIdx.y * 32;
  int r = threadIdx.x >> 5, c = threadIdx.x & 31;
#pragma unroll
  for (int i = 0; i < 4; ++i)
    t[r + i * 8][c] = (_Float16)W[(size_t)(k0 + r + i * 8) * Dv + n0 + c];
  __syncthreads();
#pragma unroll
  for (int i = 0; i < 4; ++i)
    WT[(size_t)(n0 + r + i * 8) * Dv + k0 + c] = t[c][r + i * 8];
}

// --- 3. projection GEMM: Out = X @ W  (via WT as B^T). trans=1 -> write Out^T (for V) ---
__global__ __launch_bounds__(256) void ca_proj(const _Float16* __restrict__ X,
                                               const _Float16* __restrict__ WT,
                                               _Float16* __restrict__ Out, int trans) {
  __shared__ _Float16 As[128 * LSTR], Bs[128 * LSTR];
  f32x4 acc[4][4];
  ZERO_ACC(acc);
  int m0 = blockIdx.x * 128, n0 = blockIdx.y * 128;
  gemm_core(X + (size_t)m0 * Dv, Dv, WT + (size_t)n0 * Dv, Dv, Dv / 32, As, Bs, acc);
  int lane = threadIdx.x & 63, wave = threadIdx.x >> 6;
  int wm = wave >> 1, wn = wave & 1, ll = lane & 15, quad = lane >> 4;
  if (!trans) {
#pragma unroll
    for (int mi = 0; mi < 4; ++mi)
#pragma unroll
      for (int ni = 0; ni < 4; ++ni) {
        int gc = n0 + wn * 64 + ni * 16 + ll;
#pragma unroll
        for (int r = 0; r < 4; ++r) {
          int gr = m0 + wm * 64 + mi * 16 + quad * 4 + r;
          Out[(size_t)gr * Dv + gc] = (_Float16)acc[mi][ni][r];
        }
      }
  } else {
    // Out^T: [d_out][B*S]; 4 regs = 4 consecutive rows -> contiguous 8B store
#pragma unroll
    for (int mi = 0; mi < 4; ++mi)
#pragma unroll
      for (int ni = 0; ni < 4; ++ni) {
        int gc = n0 + wn * 64 + ni * 16 + ll;
        int gr = m0 + wm * 64 + mi * 16 + quad * 4;
        f16x4 v;
#pragma unroll
        for (int r = 0; r < 4; ++r) v[r] = (_Float16)acc[mi][ni][r];
        *(f16x4*)(Out + (size_t)gc * (Bv * Sv) + gr) = v;
      }
  }
}

// --- 4. scores: U = exp(QK^T / 32), causal tiles only ---
__global__ __launch_bounds__(256) void ca_score(const _Float16* __restrict__ Q,
                                                const _Float16* __restrict__ Km,
                                                _Float16* __restrict__ U) {
  int kt = blockIdx.x, qt = blockIdx.y, b = blockIdx.z;
  if (kt > qt) return;
  __shared__ _Float16 As[128 * LSTR], Bs[128 * LSTR];
  f32x4 acc[4][4];
  ZERO_ACC(acc);
  const _Float16* Qb = Q + ((size_t)b * Sv + qt * 128) * Dv;
  const _Float16* Kb = Km + ((size_t)b * Sv + kt * 128) * Dv;
  gemm_core(Qb, Dv, Kb, Dv, Dv / 32, As, Bs, acc);
  int lane = threadIdx.x & 63, wave = threadIdx.x >> 6;
  int wm = wave >> 1, wn = wave & 1, ll = lane & 15, quad = lane >> 4;
#pragma unroll
  for (int mi = 0; mi < 4; ++mi)
#pragma unroll
    for (int ni = 0; ni < 4; ++ni) {
      int kc = kt * 128 + wn * 64 + ni * 16 + ll;
#pragma unroll
      for (int r = 0; r < 4; ++r) {
        int qr = qt * 128 + wm * 64 + mi * 16 + quad * 4 + r;
        float s = acc[mi][ni][r] * 0.03125f;  // 1/sqrt(1024)
        float u = (kc > qr) ? 0.f : __expf(fminf(fmaxf(s, -15.f), 10.f));
        U[((size_t)b * Sv + qr) * Sv + kc] = (_Float16)u;
      }
    }
}

// --- 5. row sums -> 1/l ---
__global__ __launch_bounds__(256) void ca_rowsum(const _Float16* __restrict__ U,
                                                 float* __restrict__ invl) {
  int rg = blockIdx.x;
  int b = rg >> 11, q = rg & (Sv - 1);
  int lim = ((q >> 7) + 1) << 7;
  const _Float16* row = U + ((size_t)b * Sv + q) * Sv;
  float s = 0.f;
  for (int k = threadIdx.x * 8; k < lim; k += 2048) {
    f16x8 v = *(const f16x8*)(row + k);
#pragma unroll
    for (int j = 0; j < 8; ++j) s += (float)v[j];
  }
#pragma unroll
  for (int o = 32; o >= 1; o >>= 1) s += __shfl_down(s, o);
  __shared__ float wsum[4];
  if ((threadIdx.x & 63) == 0) wsum[threadIdx.x >> 6] = s;
  __syncthreads();
  if (threadIdx.x == 0) invl[rg] = 1.f / (wsum[0] + wsum[1] + wsum[2] + wsum[3]);
}

// --- 6. PV GEMM: out = (U @ V) * invl ---
__global__ __launch_bounds__(256) void ca_pv(const _Float16* __restrict__ U,
                                             const _Float16* __restrict__ Vt,
                                             const float* __restrict__ invl,
                                             float* __restrict__ Out) {
  int nt = blockIdx.x, qt = blockIdx.y, b = blockIdx.z;
  __shared__ _Float16 As[128 * LSTR], Bs[128 * LSTR];
  f32x4 acc[4][4];
  ZERO_ACC(acc);
  const _Float16* Ab = U + ((size_t)b * Sv + qt * 128) * Sv;
  const _Float16* Bb = Vt + (size_t)(nt * 128) * (Bv * Sv) + (size_t)b * Sv;
  gemm_core(Ab, Sv, Bb, Bv * Sv, (qt + 1) * 4, As, Bs, acc);
  int lane = threadIdx.x & 63, wave = threadIdx.x >> 6;
  int wm = wave >> 1, wn = wave & 1, ll = lane & 15, quad = lane >> 4;
#pragma unroll
  for (int mi = 0; mi < 4; ++mi)
#pragma unroll
    for (int ni = 0; ni < 4; ++ni) {
      int oc = nt * 128 + wn * 64 + ni * 16 + ll;
#pragma unroll
      for (int r = 0; r < 4; ++r) {
        int qr = qt * 128 + wm * 64 + mi * 16 + quad * 4 + r;
        Out[((size_t)b * Sv + qr) * Dv + oc] = acc[mi][ni][r] * invl[b * Sv + qr];
      }
    }
}

extern "C" void kernel_launch(void* const* d_in, const int* in_sizes, int n_in,
                              void* d_out, int out_size, void* d_ws, size_t ws_size,
                              hipStream_t stream) {
  const float* x  = (const float*)d_in[0];
  const float* Wq = (const float*)d_in[1];
  const float* Wk = (const float*)d_in[2];
  const float* Wv = (const float*)d_in[3];
  float* out = (float*)d_out;

  char* ws = (char*)d_ws;
  size_t off = 0;
  const size_t M = (size_t)Bv * Sv;           // 16384
  _Float16* xh  = (_Float16*)(ws + off); off += M * Dv * 2;        // 32 MB
  _Float16* WTq = (_Float16*)(ws + off); off += (size_t)Dv * Dv * 2;
  _Float16* WTk = (_Float16*)(ws + off); off += (size_t)Dv * Dv * 2;
  _Float16* WTv = (_Float16*)(ws + off); off += (size_t)Dv * Dv * 2;
  _Float16* Q   = (_Float16*)(ws + off); off += M * Dv * 2;        // 32 MB
  _Float16* Km  = (_Float16*)(ws + off); off += M * Dv * 2;        // 32 MB
  _Float16* Vt  = (_Float16*)(ws + off); off += M * Dv * 2;        // 32 MB (transposed)
  _Float16* U   = (_Float16*)(ws + off); off += (size_t)Bv * Sv * Sv * 2;  // 64 MB
  float*    invl = (float*)(ws + off);   off += M * 4;

  ca_cast<<<(M * Dv) / (8 * 256), 256, 0, stream>>>(x, xh);
  ca_transpose<<<dim3(32, 32), 256, 0, stream>>>(Wq, WTq);
  ca_transpose<<<dim3(32, 32), 256, 0, stream>>>(Wk, WTk);
  ca_transpose<<<dim3(32, 32), 256, 0, stream>>>(Wv, WTv);

  ca_proj<<<dim3(M / 128, Dv / 128), 256, 0, stream>>>(xh, WTq, Q, 0);
  ca_proj<<<dim3(M / 128, Dv / 128), 256, 0, stream>>>(xh, WTk, Km, 0);
  ca_proj<<<dim3(M / 128, Dv / 128), 256, 0, stream>>>(xh, WTv, Vt, 1);

  ca_score<<<dim3(Sv / 128, Sv / 128, Bv), 256, 0, stream>>>(Q, Km, U);
  ca_rowsum<<<M, 256, 0, stream>>>(U, invl);
  ca_pv<<<dim3(Dv / 128, Sv / 128, Bv), 256, 0, stream>>>(U, Vt, invl, out);
}

// Round 2
// 451.094 us; speedup vs baseline: 1.0803x; 1.0803x over previous
//
#include <hip/hip_runtime.h>

// CausalAttention: B=8, S=2048, D_IN=D_OUT=1024, single head, causal, fp32 I/O.
// Pipeline (all fp16 MFMA 16x16x32, fp32 accum):
//   1. cast x -> xh (fp16)
//   2. transpose+cast Wq,Wk,Wv -> WT (d_out-major, fp16)
//   3. GEMM: Q = xh@Wq, K = xh@Wk (row-major), V -> Vt (transposed output)
//   4. score kernel: U[b,q,k] = exp(q.k/32) fp16, causal tiles only, masked diag
//   5. rowsum: invl[b,q] = 1/sum_k U
//   6. PV GEMM: out = (U @ V) * invl   (fp32 stores)
//
// R2: staging via __builtin_amdgcn_global_load_lds width=16 (m97 ladder step),
//     UNPADDED stride-32 LDS tiles (pad caused 8.9M bank conflicts in R1;
//     unpadded => each wave's ds_read_b128 fragment covers a contiguous 1KB
//     block = conflict-free, and layout is lane-ordered for global_load_lds).

#define Bv 8
#define Sv 2048
#define Dv 1024
#define BK 32

typedef _Float16 f16x8 __attribute__((ext_vector_type(8)));
typedef _Float16 f16x4 __attribute__((ext_vector_type(4)));
typedef float    f32x4 __attribute__((ext_vector_type(4)));

// Stage a 128x32 f16 tile (8KB) async global->LDS, unpadded (row stride 32).
// Wave w stages rows [32w, 32w+32); instr j covers 16 rows (1024B);
// lane i -> LDS base + i*16 (wave-uniform base per the m104/m108 constraint).
__device__ __forceinline__ void stage_async(const _Float16* __restrict__ g, int ld,
                                            _Float16* lds, int tid) {
  int lane = tid & 63, w = tid >> 6;
  int row = lane >> 2;            // 0..15 within 16-row chunk
  int col = (lane & 3) * 8;       // 0,8,16,24 f16 (16B quarters)
  const _Float16* gp = g + (size_t)(w * 32 + row) * ld + col;
  _Float16* lp = lds + w * 1024;  // wave-uniform
#pragma unroll
  for (int j = 0; j < 2; ++j) {
    __builtin_amdgcn_global_load_lds(
        (const __attribute__((address_space(1))) void*)(gp + (size_t)(j * 16) * ld),
        (__attribute__((address_space(3))) void*)(lp + j * 512), 16, 0, 0);
  }
}

__device__ __forceinline__ void mma_step(const _Float16* As, const _Float16* Bs,
                                         int wm, int wn, int lane, f32x4 acc[4][4]) {
  int ll = lane & 15, quad = lane >> 4;
  f16x8 a[4], b[4];
#pragma unroll
  for (int mi = 0; mi < 4; ++mi)
    a[mi] = *(const f16x8*)(As + (wm * 64 + mi * 16 + ll) * BK + quad * 8);
#pragma unroll
  for (int ni = 0; ni < 4; ++ni)
    b[ni] = *(const f16x8*)(Bs + (wn * 64 + ni * 16 + ll) * BK + quad * 8);
#pragma unroll
  for (int mi = 0; mi < 4; ++mi)
#pragma unroll
    for (int ni = 0; ni < 4; ++ni)
      acc[mi][ni] = __builtin_amdgcn_mfma_f32_16x16x32_f16(a[mi], b[ni], acc[mi][ni], 0, 0, 0);
}

__device__ __forceinline__ void gemm_core(const _Float16* __restrict__ A, int lda,
                                          const _Float16* __restrict__ B, int ldb,
                                          int ktiles, _Float16* As, _Float16* Bs,
                                          f32x4 acc[4][4]) {
  int tid  = threadIdx.x;
  int lane = tid & 63, wave = tid >> 6;
  int wm = wave >> 1, wn = wave & 1;
  for (int kt = 0; kt < ktiles; ++kt) {
    stage_async(A + kt * BK, lda, As, tid);
    stage_async(B + kt * BK, ldb, Bs, tid);
    __syncthreads();   // drains vmcnt -> LDS tile complete
    mma_step(As, Bs, wm, wn, lane, acc);
    __syncthreads();
  }
}

#define ZERO_ACC(acc)                              \
  _Pragma("unroll") for (int i_ = 0; i_ < 4; ++i_) \
  _Pragma("unroll") for (int j_ = 0; j_ < 4; ++j_) \
      acc[i_][j_] = (f32x4){0.f, 0.f, 0.f, 0.f};

// --- 1. cast x (fp32) -> fp16, 8 elems/thread ---
__global__ __launch_bounds__(256) void ca_cast(const float* __restrict__ x,
                                               _Float16* __restrict__ y) {
  int i = (blockIdx.x * 256 + threadIdx.x) * 8;
  f32x4 a = *(const f32x4*)(x + i);
  f32x4 b = *(const f32x4*)(x + i + 4);
  f16x8 h;
#pragma unroll
  for (int j = 0; j < 4; ++j) { h[j] = (_Float16)a[j]; h[4 + j] = (_Float16)b[j]; }
  *(f16x8*)(y + i) = h;
}

// --- 2. transpose+cast W (K x N fp32) -> WT (N x K fp16) ---
__global__ __launch_bounds__(256) void ca_transpose(const float* __restrict__ W,
                                                    _Float16* __restrict__ WT) {
  __shared__ _Float16 t[32][33];
  int k0 = blockIdx.x * 32, n0 = blockIdx.y * 32;
  int r = threadIdx.x >> 5, c = threadIdx.x & 31;
#pragma unroll
  for (int i = 0; i < 4; ++i)
    t[r + i * 8][c] = (_Float16)W[(size_t)(k0 + r + i * 8) * Dv + n0 + c];
  __syncthreads();
#pragma unroll
  for (int i = 0; i < 4; ++i)
    WT[(size_t)(n0 + r + i * 8) * Dv + k0 + c] = t[c][r + i * 8];
}

// --- 3. projection GEMM: Out = X @ W  (via WT as B^T). trans=1 -> write Out^T (for V) ---
__global__ __launch_bounds__(256) void ca_proj(const _Float16* __restrict__ X,
                                               const _Float16* __restrict__ WT,
                                               _Float16* __restrict__ Out, int trans) {
  __shared__ _Float16 As[128 * BK], Bs[128 * BK];
  f32x4 acc[4][4];
  ZERO_ACC(acc);
  int m0 = blockIdx.x * 128, n0 = blockIdx.y * 128;
  gemm_core(X + (size_t)m0 * Dv, Dv, WT + (size_t)n0 * Dv, Dv, Dv / BK, As, Bs, acc);
  int lane = threadIdx.x & 63, wave = threadIdx.x >> 6;
  int wm = wave >> 1, wn = wave & 1, ll = lane & 15, quad = lane >> 4;
  if (!trans) {
#pragma unroll
    for (int mi = 0; mi < 4; ++mi)
#pragma unroll
      for (int ni = 0; ni < 4; ++ni) {
        int gc = n0 + wn * 64 + ni * 16 + ll;
#pragma unroll
        for (int r = 0; r < 4; ++r) {
          int gr = m0 + wm * 64 + mi * 16 + quad * 4 + r;
          Out[(size_t)gr * Dv + gc] = (_Float16)acc[mi][ni][r];
        }
      }
  } else {
    // Out^T: [d_out][B*S]; 4 regs = 4 consecutive rows -> contiguous 8B store
#pragma unroll
    for (int mi = 0; mi < 4; ++mi)
#pragma unroll
      for (int ni = 0; ni < 4; ++ni) {
        int gc = n0 + wn * 64 + ni * 16 + ll;
        int gr = m0 + wm * 64 + mi * 16 + quad * 4;
        f16x4 v;
#pragma unroll
        for (int r = 0; r < 4; ++r) v[r] = (_Float16)acc[mi][ni][r];
        *(f16x4*)(Out + (size_t)gc * (Bv * Sv) + gr) = v;
      }
  }
}

// --- 4. scores: U = exp(QK^T / 32), causal tiles only ---
__global__ __launch_bounds__(256) void ca_score(const _Float16* __restrict__ Q,
                                                const _Float16* __restrict__ Km,
                                                _Float16* __restrict__ U) {
  int kt = blockIdx.x, qt = blockIdx.y, b = blockIdx.z;
  if (kt > qt) return;
  __shared__ _Float16 As[128 * BK], Bs[128 * BK];
  f32x4 acc[4][4];
  ZERO_ACC(acc);
  const _Float16* Qb = Q + ((size_t)b * Sv + qt * 128) * Dv;
  const _Float16* Kb = Km + ((size_t)b * Sv + kt * 128) * Dv;
  gemm_core(Qb, Dv, Kb, Dv, Dv / BK, As, Bs, acc);
  int lane = threadIdx.x & 63, wave = threadIdx.x >> 6;
  int wm = wave >> 1, wn = wave & 1, ll = lane & 15, quad = lane >> 4;
#pragma unroll
  for (int mi = 0; mi < 4; ++mi)
#pragma unroll
    for (int ni = 0; ni < 4; ++ni) {
      int kc = kt * 128 + wn * 64 + ni * 16 + ll;
#pragma unroll
      for (int r = 0; r < 4; ++r) {
        int qr = qt * 128 + wm * 64 + mi * 16 + quad * 4 + r;
        float s = acc[mi][ni][r] * 0.03125f;  // 1/sqrt(1024)
        float u = (kc > qr) ? 0.f : __expf(fminf(fmaxf(s, -15.f), 10.f));
        U[((size_t)b * Sv + qr) * Sv + kc] = (_Float16)u;
      }
    }
}

// --- 5. row sums -> 1/l ---
__global__ __launch_bounds__(256) void ca_rowsum(const _Float16* __restrict__ U,
                                                 float* __restrict__ invl) {
  int rg = blockIdx.x;
  int b = rg >> 11, q = rg & (Sv - 1);
  int lim = ((q >> 7) + 1) << 7;
  const _Float16* row = U + ((size_t)b * Sv + q) * Sv;
  float s = 0.f;
  for (int k = threadIdx.x * 8; k < lim; k += 2048) {
    f16x8 v = *(const f16x8*)(row + k);
#pragma unroll
    for (int j = 0; j < 8; ++j) s += (float)v[j];
  }
#pragma unroll
  for (int o = 32; o >= 1; o >>= 1) s += __shfl_down(s, o);
  __shared__ float wsum[4];
  if ((threadIdx.x & 63) == 0) wsum[threadIdx.x >> 6] = s;
  __syncthreads();
  if (threadIdx.x == 0) invl[rg] = 1.f / (wsum[0] + wsum[1] + wsum[2] + wsum[3]);
}

// --- 6. PV GEMM: out = (U @ V) * invl ---
__global__ __launch_bounds__(256) void ca_pv(const _Float16* __restrict__ U,
                                             const _Float16* __restrict__ Vt,
                                             const float* __restrict__ invl,
                                             float* __restrict__ Out) {
  int nt = blockIdx.x, qt = blockIdx.y, b = blockIdx.z;
  __shared__ _Float16 As[128 * BK], Bs[128 * BK];
  f32x4 acc[4][4];
  ZERO_ACC(acc);
  const _Float16* Ab = U + ((size_t)b * Sv + qt * 128) * Sv;
  const _Float16* Bb = Vt + (size_t)(nt * 128) * (Bv * Sv) + (size_t)b * Sv;
  gemm_core(Ab, Sv, Bb, Bv * Sv, (qt + 1) * 4, As, Bs, acc);
  int lane = threadIdx.x & 63, wave = threadIdx.x >> 6;
  int wm = wave >> 1, wn = wave & 1, ll = lane & 15, quad = lane >> 4;
#pragma unroll
  for (int mi = 0; mi < 4; ++mi)
#pragma unroll
    for (int ni = 0; ni < 4; ++ni) {
      int oc = nt * 128 + wn * 64 + ni * 16 + ll;
#pragma unroll
      for (int r = 0; r < 4; ++r) {
        int qr = qt * 128 + wm * 64 + mi * 16 + quad * 4 + r;
        Out[((size_t)b * Sv + qr) * Dv + oc] = acc[mi][ni][r] * invl[b * Sv + qr];
      }
    }
}

extern "C" void kernel_launch(void* const* d_in, const int* in_sizes, int n_in,
                              void* d_out, int out_size, void* d_ws, size_t ws_size,
                              hipStream_t stream) {
  const float* x  = (const float*)d_in[0];
  const float* Wq = (const float*)d_in[1];
  const float* Wk = (const float*)d_in[2];
  const float* Wv = (const float*)d_in[3];
  float* out = (float*)d_out;

  char* ws = (char*)d_ws;
  size_t off = 0;
  const size_t M = (size_t)Bv * Sv;           // 16384
  _Float16* xh  = (_Float16*)(ws + off); off += M * Dv * 2;        // 32 MB
  _Float16* WTq = (_Float16*)(ws + off); off += (size_t)Dv * Dv * 2;
  _Float16* WTk = (_Float16*)(ws + off); off += (size_t)Dv * Dv * 2;
  _Float16* WTv = (_Float16*)(ws + off); off += (size_t)Dv * Dv * 2;
  _Float16* Q   = (_Float16*)(ws + off); off += M * Dv * 2;        // 32 MB
  _Float16* Km  = (_Float16*)(ws + off); off += M * Dv * 2;        // 32 MB
  _Float16* Vt  = (_Float16*)(ws + off); off += M * Dv * 2;        // 32 MB (transposed)
  _Float16* U   = (_Float16*)(ws + off); off += (size_t)Bv * Sv * Sv * 2;  // 64 MB
  float*    invl = (float*)(ws + off);   off += M * 4;

  ca_cast<<<(M * Dv) / (8 * 256), 256, 0, stream>>>(x, xh);
  ca_transpose<<<dim3(32, 32), 256, 0, stream>>>(Wq, WTq);
  ca_transpose<<<dim3(32, 32), 256, 0, stream>>>(Wk, WTk);
  ca_transpose<<<dim3(32, 32), 256, 0, stream>>>(Wv, WTv);

  ca_proj<<<dim3(M / 128, Dv / 128), 256, 0, stream>>>(xh, WTq, Q, 0);
  ca_proj<<<dim3(M / 128, Dv / 128), 256, 0, stream>>>(xh, WTk, Km, 0);
  ca_proj<<<dim3(M / 128, Dv / 128), 256, 0, stream>>>(xh, WTv, Vt, 1);

  ca_score<<<dim3(Sv / 128, Sv / 128, Bv), 256, 0, stream>>>(Q, Km, U);
  ca_rowsum<<<M, 256, 0, stream>>>(U, invl);
  ca_pv<<<dim3(Dv / 128, Sv / 128, Bv), 256, 0, stream>>>(U, Vt, invl, out);
}

// Round 3
// 449.953 us; speedup vs baseline: 1.0831x; 1.0025x over previous
//
#include <hip/hip_runtime.h>

// CausalAttention: B=8, S=2048, D_IN=D_OUT=1024, single head, causal, fp32 I/O.
// Pipeline (all fp16 MFMA 16x16x32, fp32 accum):
//   1. cast x -> xh (fp16); transpose+cast Wq,Wk,Wv -> WT (d_out-major, fp16)
//   2. ca_qkv: fused GEMM Q = xh@Wq, K = xh@Wk (row-major), V -> Vt (transposed)
//   3. ca_score: U[b,q,k] = exp(q.k/32) fp16, causal tiles only, masked diag
//   4. ca_rowsum: invl[b,q] = 1/sum_k U
//   5. ca_pv: out = (U @ V) * invl   (fp32 stores)
//
// R3: K-loop restructured to prefetch-dbuf, ONE barrier per iter: after the
//     barrier releasing buf[cur], issue global_load_lds for tile k+1 into
//     buf[cur^1], then mma on buf[cur] -> load flight overlaps compute
//     (R2 was a latency convoy: all pipes <25% busy, wall 3x busiest pipe).

#define Bv 8
#define Sv 2048
#define Dv 1024
#define BK 32

typedef _Float16 f16x8 __attribute__((ext_vector_type(8)));
typedef _Float16 f16x4 __attribute__((ext_vector_type(4)));
typedef float    f32x4 __attribute__((ext_vector_type(4)));

// Stage a 128x32 f16 tile (8KB) async global->LDS, unpadded (row stride 32).
// Wave w stages rows [32w, 32w+32); instr j covers 16 rows (1024B);
// lane i -> LDS base + i*16 (wave-uniform base per the m104/m108 constraint).
__device__ __forceinline__ void stage_async(const _Float16* __restrict__ g, int ld,
                                            _Float16* lds, int tid) {
  int lane = tid & 63, w = tid >> 6;
  int row = lane >> 2;            // 0..15 within 16-row chunk
  int col = (lane & 3) * 8;       // 0,8,16,24 f16 (16B quarters)
  const _Float16* gp = g + (size_t)(w * 32 + row) * ld + col;
  _Float16* lp = lds + w * 1024;  // wave-uniform
#pragma unroll
  for (int j = 0; j < 2; ++j) {
    __builtin_amdgcn_global_load_lds(
        (const __attribute__((address_space(1))) void*)(gp + (size_t)(j * 16) * ld),
        (__attribute__((address_space(3))) void*)(lp + j * 512), 16, 0, 0);
  }
}

__device__ __forceinline__ void mma_step(const _Float16* As, const _Float16* Bs,
                                         int wm, int wn, int lane, f32x4 acc[4][4]) {
  int ll = lane & 15, quad = lane >> 4;
  f16x8 a[4], b[4];
#pragma unroll
  for (int mi = 0; mi < 4; ++mi)
    a[mi] = *(const f16x8*)(As + (wm * 64 + mi * 16 + ll) * BK + quad * 8);
#pragma unroll
  for (int ni = 0; ni < 4; ++ni)
    b[ni] = *(const f16x8*)(Bs + (wn * 64 + ni * 16 + ll) * BK + quad * 8);
#pragma unroll
  for (int mi = 0; mi < 4; ++mi)
#pragma unroll
    for (int ni = 0; ni < 4; ++ni)
      acc[mi][ni] = __builtin_amdgcn_mfma_f32_16x16x32_f16(a[mi], b[ni], acc[mi][ni], 0, 0, 0);
}

// Prefetch double-buffered K-loop: one barrier per iteration.
// Barrier at top of iter k guarantees (a) buf[cur]'s DMA drained (vmcnt(0)),
// (b) all waves finished iter k-1's mma on buf[cur^1] -> safe to overwrite.
__device__ __forceinline__ void gemm_dbuf(const _Float16* __restrict__ A, int lda,
                                          const _Float16* __restrict__ B, int ldb,
                                          int ktiles,
                                          _Float16 (*As)[128 * BK], _Float16 (*Bs)[128 * BK],
                                          f32x4 acc[4][4]) {
  int tid  = threadIdx.x;
  int lane = tid & 63, wave = tid >> 6;
  int wm = wave >> 1, wn = wave & 1;
  stage_async(A, lda, As[0], tid);
  stage_async(B, ldb, Bs[0], tid);
  for (int kt = 0; kt < ktiles; ++kt) {
    int cur = kt & 1;
    __syncthreads();
    if (kt + 1 < ktiles) {
      stage_async(A + (kt + 1) * BK, lda, As[cur ^ 1], tid);
      stage_async(B + (kt + 1) * BK, ldb, Bs[cur ^ 1], tid);
    }
    mma_step(As[cur], Bs[cur], wm, wn, lane, acc);
  }
}

#define ZERO_ACC(acc)                              \
  _Pragma("unroll") for (int i_ = 0; i_ < 4; ++i_) \
  _Pragma("unroll") for (int j_ = 0; j_ < 4; ++j_) \
      acc[i_][j_] = (f32x4){0.f, 0.f, 0.f, 0.f};

// --- 1a. cast x (fp32) -> fp16, 8 elems/thread ---
__global__ __launch_bounds__(256) void ca_cast(const float* __restrict__ x,
                                               _Float16* __restrict__ y) {
  int i = (blockIdx.x * 256 + threadIdx.x) * 8;
  f32x4 a = *(const f32x4*)(x + i);
  f32x4 b = *(const f32x4*)(x + i + 4);
  f16x8 h;
#pragma unroll
  for (int j = 0; j < 4; ++j) { h[j] = (_Float16)a[j]; h[4 + j] = (_Float16)b[j]; }
  *(f16x8*)(y + i) = h;
}

// --- 1b. transpose+cast W (K x N fp32) -> WT (N x K fp16), z selects matrix ---
__global__ __launch_bounds__(256) void ca_transpose(const float* __restrict__ W0,
                                                    const float* __restrict__ W1,
                                                    const float* __restrict__ W2,
                                                    _Float16* __restrict__ T0,
                                                    _Float16* __restrict__ T1,
                                                    _Float16* __restrict__ T2) {
  const float* W = blockIdx.z == 0 ? W0 : blockIdx.z == 1 ? W1 : W2;
  _Float16* WT   = blockIdx.z == 0 ? T0 : blockIdx.z == 1 ? T1 : T2;
  __shared__ _Float16 t[32][33];
  int k0 = blockIdx.x * 32, n0 = blockIdx.y * 32;
  int r = threadIdx.x >> 5, c = threadIdx.x & 31;
#pragma unroll
  for (int i = 0; i < 4; ++i)
    t[r + i * 8][c] = (_Float16)W[(size_t)(k0 + r + i * 8) * Dv + n0 + c];
  __syncthreads();
#pragma unroll
  for (int i = 0; i < 4; ++i)
    WT[(size_t)(n0 + r + i * 8) * Dv + k0 + c] = t[c][r + i * 8];
}

// --- 2. fused QKV projection: nt 0..7 -> Q, 8..15 -> K, 16..23 -> Vt(transposed) ---
__global__ __launch_bounds__(256) void ca_qkv(const _Float16* __restrict__ X,
                                              const _Float16* __restrict__ WTq,
                                              const _Float16* __restrict__ WTk,
                                              const _Float16* __restrict__ WTv,
                                              _Float16* __restrict__ Q,
                                              _Float16* __restrict__ K,
                                              _Float16* __restrict__ Vt) {
  __shared__ _Float16 As[2][128 * BK], Bs[2][128 * BK];
  f32x4 acc[4][4];
  ZERO_ACC(acc);
  int nt = blockIdx.x;             // 0..23, fastest -> 24 blocks share one A-tile
  int m0 = blockIdx.y * 128;
  int which = nt >> 3;
  int n0 = (nt & 7) * 128;
  const _Float16* WT = which == 0 ? WTq : which == 1 ? WTk : WTv;
  gemm_dbuf(X + (size_t)m0 * Dv, Dv, WT + (size_t)n0 * Dv, Dv, Dv / BK, As, Bs, acc);
  int lane = threadIdx.x & 63, wave = threadIdx.x >> 6;
  int wm = wave >> 1, wn = wave & 1, ll = lane & 15, quad = lane >> 4;
  if (which < 2) {
    _Float16* Out = which == 0 ? Q : K;
#pragma unroll
    for (int mi = 0; mi < 4; ++mi)
#pragma unroll
      for (int ni = 0; ni < 4; ++ni) {
        int gc = n0 + wn * 64 + ni * 16 + ll;
#pragma unroll
        for (int r = 0; r < 4; ++r) {
          int gr = m0 + wm * 64 + mi * 16 + quad * 4 + r;
          Out[(size_t)gr * Dv + gc] = (_Float16)acc[mi][ni][r];
        }
      }
  } else {
    // Vt: [d_out][B*S]; 4 regs = 4 consecutive rows -> contiguous 8B store
#pragma unroll
    for (int mi = 0; mi < 4; ++mi)
#pragma unroll
      for (int ni = 0; ni < 4; ++ni) {
        int gc = n0 + wn * 64 + ni * 16 + ll;
        int gr = m0 + wm * 64 + mi * 16 + quad * 4;
        f16x4 v;
#pragma unroll
        for (int r = 0; r < 4; ++r) v[r] = (_Float16)acc[mi][ni][r];
        *(f16x4*)(Vt + (size_t)gc * (Bv * Sv) + gr) = v;
      }
  }
}

// --- 3. scores: U = exp(QK^T / 32), causal tiles only ---
__global__ __launch_bounds__(256) void ca_score(const _Float16* __restrict__ Q,
                                                const _Float16* __restrict__ Km,
                                                _Float16* __restrict__ U) {
  int kt = blockIdx.x, qt = blockIdx.y, b = blockIdx.z;
  if (kt > qt) return;
  __shared__ _Float16 As[2][128 * BK], Bs[2][128 * BK];
  f32x4 acc[4][4];
  ZERO_ACC(acc);
  const _Float16* Qb = Q + ((size_t)b * Sv + qt * 128) * Dv;
  const _Float16* Kb = Km + ((size_t)b * Sv + kt * 128) * Dv;
  gemm_dbuf(Qb, Dv, Kb, Dv, Dv / BK, As, Bs, acc);
  int lane = threadIdx.x & 63, wave = threadIdx.x >> 6;
  int wm = wave >> 1, wn = wave & 1, ll = lane & 15, quad = lane >> 4;
#pragma unroll
  for (int mi = 0; mi < 4; ++mi)
#pragma unroll
    for (int ni = 0; ni < 4; ++ni) {
      int kc = kt * 128 + wn * 64 + ni * 16 + ll;
#pragma unroll
      for (int r = 0; r < 4; ++r) {
        int qr = qt * 128 + wm * 64 + mi * 16 + quad * 4 + r;
        float s = acc[mi][ni][r] * 0.03125f;  // 1/sqrt(1024)
        float u = (kc > qr) ? 0.f : __expf(fminf(fmaxf(s, -15.f), 10.f));
        U[((size_t)b * Sv + qr) * Sv + kc] = (_Float16)u;
      }
    }
}

// --- 4. row sums -> 1/l ---
__global__ __launch_bounds__(256) void ca_rowsum(const _Float16* __restrict__ U,
                                                 float* __restrict__ invl) {
  int rg = blockIdx.x;
  int b = rg >> 11, q = rg & (Sv - 1);
  int lim = ((q >> 7) + 1) << 7;
  const _Float16* row = U + ((size_t)b * Sv + q) * Sv;
  float s = 0.f;
  for (int k = threadIdx.x * 8; k < lim; k += 2048) {
    f16x8 v = *(const f16x8*)(row + k);
#pragma unroll
    for (int j = 0; j < 8; ++j) s += (float)v[j];
  }
#pragma unroll
  for (int o = 32; o >= 1; o >>= 1) s += __shfl_down(s, o);
  __shared__ float wsum[4];
  if ((threadIdx.x & 63) == 0) wsum[threadIdx.x >> 6] = s;
  __syncthreads();
  if (threadIdx.x == 0) invl[rg] = 1.f / (wsum[0] + wsum[1] + wsum[2] + wsum[3]);
}

// --- 5. PV GEMM: out = (U @ V) * invl ---
__global__ __launch_bounds__(256) void ca_pv(const _Float16* __restrict__ U,
                                             const _Float16* __restrict__ Vt,
                                             const float* __restrict__ invl,
                                             float* __restrict__ Out) {
  int nt = blockIdx.x, qt = blockIdx.y, b = blockIdx.z;
  __shared__ _Float16 As[2][128 * BK], Bs[2][128 * BK];
  f32x4 acc[4][4];
  ZERO_ACC(acc);
  const _Float16* Ab = U + ((size_t)b * Sv + qt * 128) * Sv;
  const _Float16* Bb = Vt + (size_t)(nt * 128) * (Bv * Sv) + (size_t)b * Sv;
  gemm_dbuf(Ab, Sv, Bb, Bv * Sv, (qt + 1) * 4, As, Bs, acc);
  int lane = threadIdx.x & 63, wave = threadIdx.x >> 6;
  int wm = wave >> 1, wn = wave & 1, ll = lane & 15, quad = lane >> 4;
#pragma unroll
  for (int mi = 0; mi < 4; ++mi)
#pragma unroll
    for (int ni = 0; ni < 4; ++ni) {
      int oc = nt * 128 + wn * 64 + ni * 16 + ll;
#pragma unroll
      for (int r = 0; r < 4; ++r) {
        int qr = qt * 128 + wm * 64 + mi * 16 + quad * 4 + r;
        Out[((size_t)b * Sv + qr) * Dv + oc] = acc[mi][ni][r] * invl[b * Sv + qr];
      }
    }
}

extern "C" void kernel_launch(void* const* d_in, const int* in_sizes, int n_in,
                              void* d_out, int out_size, void* d_ws, size_t ws_size,
                              hipStream_t stream) {
  const float* x  = (const float*)d_in[0];
  const float* Wq = (const float*)d_in[1];
  const float* Wk = (const float*)d_in[2];
  const float* Wv = (const float*)d_in[3];
  float* out = (float*)d_out;

  char* ws = (char*)d_ws;
  size_t off = 0;
  const size_t M = (size_t)Bv * Sv;           // 16384
  _Float16* xh  = (_Float16*)(ws + off); off += M * Dv * 2;        // 32 MB
  _Float16* WTq = (_Float16*)(ws + off); off += (size_t)Dv * Dv * 2;
  _Float16* WTk = (_Float16*)(ws + off); off += (size_t)Dv * Dv * 2;
  _Float16* WTv = (_Float16*)(ws + off); off += (size_t)Dv * Dv * 2;
  _Float16* Q   = (_Float16*)(ws + off); off += M * Dv * 2;        // 32 MB
  _Float16* Km  = (_Float16*)(ws + off); off += M * Dv * 2;        // 32 MB
  _Float16* Vt  = (_Float16*)(ws + off); off += M * Dv * 2;        // 32 MB (transposed)
  _Float16* U   = (_Float16*)(ws + off); off += (size_t)Bv * Sv * Sv * 2;  // 64 MB
  float*    invl = (float*)(ws + off);   off += M * 4;

  ca_cast<<<(M * Dv) / (8 * 256), 256, 0, stream>>>(x, xh);
  ca_transpose<<<dim3(32, 32, 3), 256, 0, stream>>>(Wq, Wk, Wv, WTq, WTk, WTv);

  ca_qkv<<<dim3(24, M / 128), 256, 0, stream>>>(xh, WTq, WTk, WTv, Q, Km, Vt);

  ca_score<<<dim3(Sv / 128, Sv / 128, Bv), 256, 0, stream>>>(Q, Km, U);
  ca_rowsum<<<M, 256, 0, stream>>>(U, invl);
  ca_pv<<<dim3(Dv / 128, Sv / 128, Bv), 256, 0, stream>>>(U, Vt, invl, out);
}

// Round 4
// 426.138 us; speedup vs baseline: 1.1436x; 1.0559x over previous
//
#include <hip/hip_runtime.h>

// CausalAttention: B=8, S=2048, D_IN=D_OUT=1024, single head, causal, fp32 I/O.
// Pipeline (all fp16 MFMA 16x16x32, fp32 accum):
//   1. cast x -> xh (fp16); transpose+cast Wq,Wk,Wv -> WT (d_out-major, fp16)
//   2. ca_qkv: fused GEMM Q = xh@Wq, K = xh@Wk (row-major), V -> Vt (transposed)
//   3. ca_score: U[b,q,k] = exp(q.k/32) fp16, causal tiles only, masked diag
//   4. ca_rowsum: invl[b,q] = 1/sum_k U
//   5. ca_pv: out = (U @ V) * invl   (fp32 stores)
//
// R4: kill steady-state VALU (R3: VALUBusy 51% > MfmaUtil 28%).
//  - K-loop unrolled x2 -> compile-time buffer index: all ds_read addresses
//    are one base VGPR + immediate offsets (buf1 = buf0 + 16384B DS imm).
//  - Staging: lane-divergent 32-bit offsets precomputed ONCE; only the
//    wave-uniform global base advances per iter (scalar adds) -> compiler
//    emits global_load_lds in saddr+voffset form, ~0 VALU/iter.
//  - LDS layout [As0|Bs0|As1|Bs1] static -> DMA destinations static.

#define Bv 8
#define Sv 2048
#define Dv 1024
#define BK 32

typedef _Float16 f16x8 __attribute__((ext_vector_type(8)));
typedef _Float16 f16x4 __attribute__((ext_vector_type(4)));
typedef float    f32x4 __attribute__((ext_vector_type(4)));

#define GLL(gp, lp)                                            \
  __builtin_amdgcn_global_load_lds(                            \
      (const __attribute__((address_space(1))) void*)(gp),     \
      (__attribute__((address_space(3))) void*)(lp), 16, 0, 0)

__device__ __forceinline__ void mma_step(const _Float16* As, const _Float16* Bs,
                                         int wm, int wn, int lane, f32x4 acc[4][4]) {
  int ll = lane & 15, quad = lane >> 4;
  f16x8 a[4], b[4];
#pragma unroll
  for (int mi = 0; mi < 4; ++mi)
    a[mi] = *(const f16x8*)(As + (wm * 64 + mi * 16 + ll) * BK + quad * 8);
#pragma unroll
  for (int ni = 0; ni < 4; ++ni)
    b[ni] = *(const f16x8*)(Bs + (wn * 64 + ni * 16 + ll) * BK + quad * 8);
#pragma unroll
  for (int mi = 0; mi < 4; ++mi)
#pragma unroll
    for (int ni = 0; ni < 4; ++ni)
      acc[mi][ni] = __builtin_amdgcn_mfma_f32_16x16x32_f16(a[mi], b[ni], acc[mi][ni], 0, 0, 0);
}

// Prefetch double-buffered K-loop, one barrier per K-tile, unrolled x2.
// ktiles must be EVEN (all call sites: 32 or (qt+1)*4).
// S layout: S[0]=As0 S[1]=Bs0 S[2]=As1 S[3]=Bs1 (each 128x32 f16 = 8KB).
// Barrier at top of each half guarantees (a) current buf's DMA drained,
// (b) all waves done with the buf about to be overwritten.
__device__ __forceinline__ void gemm_dbuf(const _Float16* __restrict__ A, int lda,
                                          const _Float16* __restrict__ B, int ldb,
                                          int ktiles, _Float16 (*S)[4096],
                                          f32x4 acc[4][4]) {
  const int tid  = threadIdx.x;
  const int lane = tid & 63, wave = tid >> 6;
  const int wm = wave >> 1, wn = wave & 1;
  // staging lane offsets (computed once; loop advances uniform bases only)
  const int srow = wave * 32 + (lane >> 2);   // 0..127
  const int scol = (lane & 3) * 8;            // 0,8,16,24
  const int loA0 = srow * lda + scol, loA1 = loA0 + 16 * lda;
  const int loB0 = srow * ldb + scol, loB1 = loB0 + 16 * ldb;
  _Float16* dA = &S[0][wave * 1024];          // wave-uniform DMA dest
  _Float16* dB = &S[1][wave * 1024];
  const _Float16* gA = A;
  const _Float16* gB = B;

#define STAGE(bi)                              \
  do {                                         \
    GLL(gA + loA0, dA + (bi) * 8192);          \
    GLL(gA + loA1, dA + (bi) * 8192 + 512);    \
    GLL(gB + loB0, dB + (bi) * 8192);          \
    GLL(gB + loB1, dB + (bi) * 8192 + 512);    \
  } while (0)

  STAGE(0);
  for (int kt = 0; kt < ktiles; kt += 2) {
    __syncthreads();
    gA += BK; gB += BK;
    STAGE(1);                                  // tile kt+1 (always valid: ktiles even)
    mma_step(S[0], S[1], wm, wn, lane, acc);
    __syncthreads();
    gA += BK; gB += BK;
    if (kt + 2 < ktiles) STAGE(0);             // tile kt+2
    mma_step(S[2], S[3], wm, wn, lane, acc);
  }
#undef STAGE
}

#define ZERO_ACC(acc)                              \
  _Pragma("unroll") for (int i_ = 0; i_ < 4; ++i_) \
  _Pragma("unroll") for (int j_ = 0; j_ < 4; ++j_) \
      acc[i_][j_] = (f32x4){0.f, 0.f, 0.f, 0.f};

// --- 1a. cast x (fp32) -> fp16, 8 elems/thread ---
__global__ __launch_bounds__(256) void ca_cast(const float* __restrict__ x,
                                               _Float16* __restrict__ y) {
  int i = (blockIdx.x * 256 + threadIdx.x) * 8;
  f32x4 a = *(const f32x4*)(x + i);
  f32x4 b = *(const f32x4*)(x + i + 4);
  f16x8 h;
#pragma unroll
  for (int j = 0; j < 4; ++j) { h[j] = (_Float16)a[j]; h[4 + j] = (_Float16)b[j]; }
  *(f16x8*)(y + i) = h;
}

// --- 1b. transpose+cast W (K x N fp32) -> WT (N x K fp16), z selects matrix ---
__global__ __launch_bounds__(256) void ca_transpose(const float* __restrict__ W0,
                                                    const float* __restrict__ W1,
                                                    const float* __restrict__ W2,
                                                    _Float16* __restrict__ T0,
                                                    _Float16* __restrict__ T1,
                                                    _Float16* __restrict__ T2) {
  const float* W = blockIdx.z == 0 ? W0 : blockIdx.z == 1 ? W1 : W2;
  _Float16* WT   = blockIdx.z == 0 ? T0 : blockIdx.z == 1 ? T1 : T2;
  __shared__ _Float16 t[32][33];
  int k0 = blockIdx.x * 32, n0 = blockIdx.y * 32;
  int r = threadIdx.x >> 5, c = threadIdx.x & 31;
#pragma unroll
  for (int i = 0; i < 4; ++i)
    t[r + i * 8][c] = (_Float16)W[(size_t)(k0 + r + i * 8) * Dv + n0 + c];
  __syncthreads();
#pragma unroll
  for (int i = 0; i < 4; ++i)
    WT[(size_t)(n0 + r + i * 8) * Dv + k0 + c] = t[c][r + i * 8];
}

// --- 2. fused QKV projection: nt 0..7 -> Q, 8..15 -> K, 16..23 -> Vt(transposed) ---
__global__ __launch_bounds__(256) void ca_qkv(const _Float16* __restrict__ X,
                                              const _Float16* __restrict__ WTq,
                                              const _Float16* __restrict__ WTk,
                                              const _Float16* __restrict__ WTv,
                                              _Float16* __restrict__ Q,
                                              _Float16* __restrict__ K,
                                              _Float16* __restrict__ Vt) {
  __shared__ _Float16 S[4][4096];
  f32x4 acc[4][4];
  ZERO_ACC(acc);
  int nt = blockIdx.x;             // 0..23, fastest -> 24 blocks share one A-tile
  int m0 = blockIdx.y * 128;
  int which = nt >> 3;
  int n0 = (nt & 7) * 128;
  const _Float16* WT = which == 0 ? WTq : which == 1 ? WTk : WTv;
  gemm_dbuf(X + (size_t)m0 * Dv, Dv, WT + (size_t)n0 * Dv, Dv, Dv / BK, S, acc);
  int lane = threadIdx.x & 63, wave = threadIdx.x >> 6;
  int wm = wave >> 1, wn = wave & 1, ll = lane & 15, quad = lane >> 4;
  if (which < 2) {
    _Float16* Out = which == 0 ? Q : K;
#pragma unroll
    for (int mi = 0; mi < 4; ++mi)
#pragma unroll
      for (int ni = 0; ni < 4; ++ni) {
        int gc = n0 + wn * 64 + ni * 16 + ll;
#pragma unroll
        for (int r = 0; r < 4; ++r) {
          int gr = m0 + wm * 64 + mi * 16 + quad * 4 + r;
          Out[(size_t)gr * Dv + gc] = (_Float16)acc[mi][ni][r];
        }
      }
  } else {
    // Vt: [d_out][B*S]; 4 regs = 4 consecutive rows -> contiguous 8B store
#pragma unroll
    for (int mi = 0; mi < 4; ++mi)
#pragma unroll
      for (int ni = 0; ni < 4; ++ni) {
        int gc = n0 + wn * 64 + ni * 16 + ll;
        int gr = m0 + wm * 64 + mi * 16 + quad * 4;
        f16x4 v;
#pragma unroll
        for (int r = 0; r < 4; ++r) v[r] = (_Float16)acc[mi][ni][r];
        *(f16x4*)(Vt + (size_t)gc * (Bv * Sv) + gr) = v;
      }
  }
}

// --- 3. scores: U = exp(QK^T / 32), causal tiles only ---
__global__ __launch_bounds__(256) void ca_score(const _Float16* __restrict__ Q,
                                                const _Float16* __restrict__ Km,
                                                _Float16* __restrict__ U) {
  int kt = blockIdx.x, qt = blockIdx.y, b = blockIdx.z;
  if (kt > qt) return;
  __shared__ _Float16 S[4][4096];
  f32x4 acc[4][4];
  ZERO_ACC(acc);
  const _Float16* Qb = Q + ((size_t)b * Sv + qt * 128) * Dv;
  const _Float16* Kb = Km + ((size_t)b * Sv + kt * 128) * Dv;
  gemm_dbuf(Qb, Dv, Kb, Dv, Dv / BK, S, acc);
  int lane = threadIdx.x & 63, wave = threadIdx.x >> 6;
  int wm = wave >> 1, wn = wave & 1, ll = lane & 15, quad = lane >> 4;
#pragma unroll
  for (int mi = 0; mi < 4; ++mi)
#pragma unroll
    for (int ni = 0; ni < 4; ++ni) {
      int kc = kt * 128 + wn * 64 + ni * 16 + ll;
#pragma unroll
      for (int r = 0; r < 4; ++r) {
        int qr = qt * 128 + wm * 64 + mi * 16 + quad * 4 + r;
        float s = acc[mi][ni][r] * 0.03125f;  // 1/sqrt(1024)
        float u = (kc > qr) ? 0.f : __expf(fminf(fmaxf(s, -15.f), 10.f));
        U[((size_t)b * Sv + qr) * Sv + kc] = (_Float16)u;
      }
    }
}

// --- 4. row sums -> 1/l ---
__global__ __launch_bounds__(256) void ca_rowsum(const _Float16* __restrict__ U,
                                                 float* __restrict__ invl) {
  int rg = blockIdx.x;
  int b = rg >> 11, q = rg & (Sv - 1);
  int lim = ((q >> 7) + 1) << 7;
  const _Float16* row = U + ((size_t)b * Sv + q) * Sv;
  float s = 0.f;
  for (int k = threadIdx.x * 8; k < lim; k += 2048) {
    f16x8 v = *(const f16x8*)(row + k);
#pragma unroll
    for (int j = 0; j < 8; ++j) s += (float)v[j];
  }
#pragma unroll
  for (int o = 32; o >= 1; o >>= 1) s += __shfl_down(s, o);
  __shared__ float wsum[4];
  if ((threadIdx.x & 63) == 0) wsum[threadIdx.x >> 6] = s;
  __syncthreads();
  if (threadIdx.x == 0) invl[rg] = 1.f / (wsum[0] + wsum[1] + wsum[2] + wsum[3]);
}

// --- 5. PV GEMM: out = (U @ V) * invl ---
__global__ __launch_bounds__(256) void ca_pv(const _Float16* __restrict__ U,
                                             const _Float16* __restrict__ Vt,
                                             const float* __restrict__ invl,
                                             float* __restrict__ Out) {
  int nt = blockIdx.x, qt = blockIdx.y, b = blockIdx.z;
  __shared__ _Float16 S[4][4096];
  f32x4 acc[4][4];
  ZERO_ACC(acc);
  const _Float16* Ab = U + ((size_t)b * Sv + qt * 128) * Sv;
  const _Float16* Bb = Vt + (size_t)(nt * 128) * (Bv * Sv) + (size_t)b * Sv;
  gemm_dbuf(Ab, Sv, Bb, Bv * Sv, (qt + 1) * 4, S, acc);   // ktiles multiple of 4
  int lane = threadIdx.x & 63, wave = threadIdx.x >> 6;
  int wm = wave >> 1, wn = wave & 1, ll = lane & 15, quad = lane >> 4;
#pragma unroll
  for (int mi = 0; mi < 4; ++mi)
#pragma unroll
    for (int ni = 0; ni < 4; ++ni) {
      int oc = nt * 128 + wn * 64 + ni * 16 + ll;
#pragma unroll
      for (int r = 0; r < 4; ++r) {
        int qr = qt * 128 + wm * 64 + mi * 16 + quad * 4 + r;
        Out[((size_t)b * Sv + qr) * Dv + oc] = acc[mi][ni][r] * invl[b * Sv + qr];
      }
    }
}

extern "C" void kernel_launch(void* const* d_in, const int* in_sizes, int n_in,
                              void* d_out, int out_size, void* d_ws, size_t ws_size,
                              hipStream_t stream) {
  const float* x  = (const float*)d_in[0];
  const float* Wq = (const float*)d_in[1];
  const float* Wk = (const float*)d_in[2];
  const float* Wv = (const float*)d_in[3];
  float* out = (float*)d_out;

  char* ws = (char*)d_ws;
  size_t off = 0;
  const size_t M = (size_t)Bv * Sv;           // 16384
  _Float16* xh  = (_Float16*)(ws + off); off += M * Dv * 2;        // 32 MB
  _Float16* WTq = (_Float16*)(ws + off); off += (size_t)Dv * Dv * 2;
  _Float16* WTk = (_Float16*)(ws + off); off += (size_t)Dv * Dv * 2;
  _Float16* WTv = (_Float16*)(ws + off); off += (size_t)Dv * Dv * 2;
  _Float16* Q   = (_Float16*)(ws + off); off += M * Dv * 2;        // 32 MB
  _Float16* Km  = (_Float16*)(ws + off); off += M * Dv * 2;        // 32 MB
  _Float16* Vt  = (_Float16*)(ws + off); off += M * Dv * 2;        // 32 MB (transposed)
  _Float16* U   = (_Float16*)(ws + off); off += (size_t)Bv * Sv * Sv * 2;  // 64 MB
  float*    invl = (float*)(ws + off);   off += M * 4;

  ca_cast<<<(M * Dv) / (8 * 256), 256, 0, stream>>>(x, xh);
  ca_transpose<<<dim3(32, 32, 3), 256, 0, stream>>>(Wq, Wk, Wv, WTq, WTk, WTv);

  ca_qkv<<<dim3(24, M / 128), 256, 0, stream>>>(xh, WTq, WTk, WTv, Q, Km, Vt);

  ca_score<<<dim3(Sv / 128, Sv / 128, Bv), 256, 0, stream>>>(Q, Km, U);
  ca_rowsum<<<M, 256, 0, stream>>>(U, invl);
  ca_pv<<<dim3(Dv / 128, Sv / 128, Bv), 256, 0, stream>>>(U, Vt, invl, out);
}